// Round 2
// baseline (312.766 us; speedup 1.0000x reference)
//
#include <hip/hip_runtime.h>
#include <stdint.h>

typedef __attribute__((ext_vector_type(8))) __bf16 bf16x8;
typedef __attribute__((ext_vector_type(4))) float f32x4;
typedef __attribute__((ext_vector_type(16))) float f32x16;
typedef __attribute__((ext_vector_type(4))) short short4v;
typedef __attribute__((ext_vector_type(4))) unsigned uint4v;

// Problem constants
static constexpr int SEQ  = 2048;   // N
static constexpr int DQKV = 3072;   // q(2048) + k(512) + v(512)
static constexpr int HD   = 128;

// round-to-nearest-even fp32 -> bf16 bits
__device__ __forceinline__ short f2bf(float f) {
  unsigned u = __builtin_bit_cast(unsigned, f);
  u += 0x7fffu + ((u >> 16) & 1u);
  return (short)(u >> 16);
}

__device__ __forceinline__ unsigned pack2(float a, float b) {
  return (unsigned)(unsigned short)f2bf(a) | ((unsigned)(unsigned short)f2bf(b) << 16);
}

// async global->LDS, 16B per lane; LDS dest must be wave-uniform base + lane*16
__device__ __forceinline__ void gl_lds16(const void* g, void* l) {
  __builtin_amdgcn_global_load_lds(
      (const __attribute__((address_space(1))) void*)g,
      (__attribute__((address_space(3))) void*)l, 16, 0, 0);
}

// ---------------- fused prep: cast x + transpose-cast all weights ----------------
__global__ __launch_bounds__(256)
void prep_kernel(const float* __restrict__ x, const float* __restrict__ Wq,
                 const float* __restrict__ Wk, const float* __restrict__ Wv,
                 const float* __restrict__ Wo,
                 short* __restrict__ xb, short* __restrict__ WqkvT,
                 short* __restrict__ WoT) {
  int blk = blockIdx.x, tid = threadIdx.x;
  if (blk < 8192) {
    int i = blk * 256 + tid;
    float4 v = reinterpret_cast<const float4*>(x)[i];
    short4v o;
    o[0] = f2bf(v.x); o[1] = f2bf(v.y); o[2] = f2bf(v.z); o[3] = f2bf(v.w);
    *reinterpret_cast<short4v*>(xb + (size_t)i * 4) = o;
    return;
  }
  blk -= 8192;
  __shared__ float tile[32][33];
  const float* in; short* out; int C, bx, by;
  if (blk < 4096)      { in = Wq; out = WqkvT;                     C = 2048; bx = blk & 63; by = blk >> 6; }
  else if (blk < 5120) { int t = blk - 4096; in = Wk; out = WqkvT + (size_t)2048 * 2048; C = 512; bx = t & 15; by = t >> 4; }
  else if (blk < 6144) { int t = blk - 5120; in = Wv; out = WqkvT + (size_t)2560 * 2048; C = 512; bx = t & 15; by = t >> 4; }
  else                 { int t = blk - 6144; in = Wo; out = WoT;   C = 2048; bx = t & 63; by = t >> 6; }
  const int R = 2048;
  int c0 = bx * 32, r0 = by * 32, tx = tid & 31, ty = tid >> 5;
  for (int i = 0; i < 4; i++)
    tile[ty + i * 8][tx] = in[(size_t)(r0 + ty + i * 8) * C + c0 + tx];
  __syncthreads();
  for (int i = 0; i < 4; i++)
    out[(size_t)(c0 + ty + i * 8) * R + r0 + tx] = f2bf(tile[tx][ty + i * 8]);
}

// -------- transpose V section of qkv[4096][3072] -> vT[b*512 + gd][2048] bf16 --------
__global__ __launch_bounds__(256) void transpose_v_kernel(const short* __restrict__ qkv,
                                                          short* __restrict__ vT) {
  __shared__ short tile[32][33];
  int n0 = blockIdx.x * 32, c0 = blockIdx.y * 32, b = blockIdx.z;
  int tx = threadIdx.x & 31, ty = threadIdx.x >> 5;
  for (int i = 0; i < 4; i++)
    tile[ty + i * 8][tx] = qkv[(size_t)(b * SEQ + n0 + ty + i * 8) * DQKV + 2560 + c0 + tx];
  __syncthreads();
  for (int i = 0; i < 4; i++)
    vT[(size_t)(b * 512 + c0 + ty + i * 8) * SEQ + n0 + tx] = tile[tx][ty + i * 8];
}

// ---------------- bf16 GEMM, BK=64: C[M][N] = A[M][K] @ BT[N][K]^T ----------------
// 128x128 macro-tile, BK=64 in two 32-k slabs (32KB LDS) -> half the barrier
// crossings of BK=32 while staying at 3 blocks/CU (confirmed win R5->R6).
template <int F32OUT>
__global__ __launch_bounds__(256)
void gemm_bt_kernel(const short* __restrict__ A, const short* __restrict__ BT,
                    void* __restrict__ Cout, const float* __restrict__ bias,
                    int M, int N, int K, int qcols, float qscale) {
  __shared__ __align__(16) short As[8192];  // 2 kslabs x [128 rows][32 k]
  __shared__ __align__(16) short Bs[8192];
  const int tid = threadIdx.x, lane = tid & 63, w = tid >> 6;
  const int l15 = lane & 15, quad = lane >> 4, q8 = quad * 8;
  const int row0 = blockIdx.y * 128, col0 = blockIdx.x * 128;
  const int wm = (w >> 1) * 64, wn = (w & 1) * 64;
  f32x4 acc[4][4] = {};
  const short* ga0 = A  + (size_t)(row0 + w * 16 + (lane >> 2)) * K + (lane & 3) * 8;
  const short* gb0 = BT + (size_t)(col0 + w * 16 + (lane >> 2)) * K + (lane & 3) * 8;
  for (int kt = 0; kt < K; kt += 64) {
    for (int s = 0; s < 2; s++) {
      gl_lds16(ga0 + kt + s * 32,                  As + s * 4096 + w * 512);
      gl_lds16(ga0 + (size_t)64 * K + kt + s * 32, As + s * 4096 + 2048 + w * 512);
      gl_lds16(gb0 + kt + s * 32,                  Bs + s * 4096 + w * 512);
      gl_lds16(gb0 + (size_t)64 * K + kt + s * 32, Bs + s * 4096 + 2048 + w * 512);
    }
    __syncthreads();  // drains vmcnt -> staged tiles visible
    for (int s = 0; s < 2; s++) {
      bf16x8 af[4], bfr[4];
      for (int i = 0; i < 4; i++)
        af[i] = *reinterpret_cast<const bf16x8*>(As + s * 4096 + (wm + i * 16 + l15) * 32 + q8);
      for (int j = 0; j < 4; j++)
        bfr[j] = *reinterpret_cast<const bf16x8*>(Bs + s * 4096 + (wn + j * 16 + l15) * 32 + q8);
      for (int i = 0; i < 4; i++)
        for (int j = 0; j < 4; j++)
          acc[i][j] = __builtin_amdgcn_mfma_f32_16x16x32_bf16(af[i], bfr[j], acc[i][j], 0, 0, 0);
    }
    __syncthreads();  // protect LDS reuse next iteration
  }
  if (F32OUT) {
    float* C = (float*)Cout;
    for (int j = 0; j < 4; j++) {
      int col = col0 + wn + j * 16 + l15;
      float bv = bias[col];
      for (int i = 0; i < 4; i++)
        for (int r = 0; r < 4; r++)
          C[(size_t)(row0 + wm + i * 16 + quad * 4 + r) * N + col] = acc[i][j][r] + bv;
    }
  } else {
    short* C = (short*)Cout;
    for (int j = 0; j < 4; j++) {
      int col = col0 + wn + j * 16 + l15;
      float sc = (col < qcols) ? qscale : 1.0f;
      for (int i = 0; i < 4; i++)
        for (int r = 0; r < 4; r++)
          C[(size_t)(row0 + wm + i * 16 + quad * 4 + r) * N + col] = f2bf(acc[i][j][r] * sc);
    }
  }
}

// ---------------- flash attention, causal, GQA — 32x32 MFMA, in-register P ---------
// Round-1 regression root cause: stageK's global_load_lds were issued BEFORE the
// per-iteration V global loads; vmcnt is an in-order FIFO, so the PV-side wait on V
// became vmcnt(0) and drained the NEXT tile's staging mid-iteration -> prefetch
// destroyed, full staging latency exposed every iteration (MfmaUtil 14%, VALU 26%,
// everything idle). Fix:
//  * VMEM issue order per iteration: Q (rare) -> V(8 loads) -> stageK(4 loads) LAST,
//    pinned with sched_barrier(0). PV then waits vmcnt(4): stage loads stay in
//    flight until the next __syncthreads, like the round-0 pipeline.
//  * S-tile split into TWO independent MFMA chains (d=0..3 / d=4..7) + 16 v_add,
//    halving the dependent 32x32x16 critical path at 2 waves/SIMD.
//  * setprio(1) around both MFMA clusters.
// Structure otherwise unchanged: 32x32x16 MFMA, P entirely in registers
// (trunc-pack + permlane32_swap), V direct from L2, K LDS XOR-swizzled both-sides,
// O k-split combined through LDS twice per block.
__global__ __launch_bounds__(256, 2)
void attn_kernel(const short* __restrict__ qkv, const short* __restrict__ vT,
                 short* __restrict__ ctx) {
  __shared__ __align__(16) short Ks[2 * 8192];   // dbuf x [64 k][128 d], swizzled chunks
  __shared__ __align__(16) float Oex[2 * 4096];  // O^T exchange: waves 2,3 -> 0,1
  __shared__ float lbuf[4 * 32];                 // per-wave khalf-partial l
  const int tid = threadIdx.x, lane = tid & 63, w = tid >> 6;
  const int l31 = lane & 31, hi = lane >> 5;
  const int qh = w & 1, kh = w >> 1;
  const int idx = blockIdx.x;
  const int p = idx >> 5, h = (idx >> 1) & 15, b = idx & 1, g = h >> 2;
  const int qtA = 31 - p, qtB = p;
  const int lenA = qtA + 1, total = lenA + qtB + 1;  // == 33 for every block

  auto stageK = [&](int buf, int kt) {
    const short* gk = qkv + (size_t)(b * SEQ + kt * 64) * DQKV + 2048 + g * HD;
#pragma unroll
    for (int s = 0; s < 4; s++) {
      const int r = w * 16 + s * 4 + (lane >> 4);
      // source chunk pre-swizzled so linear LDS dest ends up XOR-swizzled
      gl_lds16(gk + (size_t)r * DQKV + ((lane & 15) ^ (r & 7)) * 8,
               Ks + buf * 8192 + (w * 16 + s * 4) * 128);
    }
  };

  bf16x8 qf[8];          // Q^T fragments for current segment (32 q rows per wave)
  f32x16 o_acc[4] = {};  // O^T[d = dt*32 + crow][q = l31], own k-half only
  float lsum = 0.f;      // running sum of P over (own khalf, own hi-subset) per q=l31

  stageK(0, 0);
  for (int t = 0; t < total; t++) {
    const int seg = (t >= lenA);
    const int kt = seg ? (t - lenA) : t;
    const int qt = seg ? qtB : qtA;
    const int cur = t & 1;
    __syncthreads();  // K buf[cur] staged; all waves done with buf[cur^1]

    if (t == 0 || t == lenA) {  // segment start: load Q fragments (oldest in FIFO)
      const short* gq = qkv + (size_t)(b * SEQ + qt * 64 + qh * 32 + l31) * DQKV + h * HD + hi * 8;
#pragma unroll
      for (int d = 0; d < 8; d++) qf[d] = *reinterpret_cast<const bf16x8*>(gq + d * 16);
    }

    // V fragments straight from L2 (vT row-major [d][k]).
    // MUST be issued before stageK: vmcnt is in-order, so PV's wait becomes
    // vmcnt(4) and the next-tile staging stays in flight across the iteration.
    bf16x8 vf[4][2];
#pragma unroll
    for (int dt = 0; dt < 4; dt++)
#pragma unroll
      for (int sub = 0; sub < 2; sub++)
        vf[dt][sub] = *reinterpret_cast<const bf16x8*>(
            vT + (size_t)(b * 512 + g * HD + dt * 32 + l31) * SEQ +
            kt * 64 + (kh * 2 + sub) * 16 + hi * 8);
    __builtin_amdgcn_sched_barrier(0);  // pin V loads above the staging intrinsics

    if (t + 1 < total) {
      const int nkt = (t + 1 >= lenA) ? (t + 1 - lenA) : (t + 1);
      stageK(cur ^ 1, nkt);  // in flight until next __syncthreads
    }
    __builtin_amdgcn_sched_barrier(0);  // keep compute below the staging issue

    // S^T quadrant [32k x 32q] = K(khalf) @ Q(qhalf)^T, two independent chains
    const short* Kb = Ks + cur * 8192;
    f32x16 sa0 = {}, sa1 = {};
    __builtin_amdgcn_s_setprio(1);
#pragma unroll
    for (int d = 0; d < 4; d++) {
      bf16x8 kf0 = *reinterpret_cast<const bf16x8*>(
          Kb + (kh * 32 + l31) * 128 + (((2 * d + hi) ^ (l31 & 7)) * 8));
      bf16x8 kf1 = *reinterpret_cast<const bf16x8*>(
          Kb + (kh * 32 + l31) * 128 + (((2 * (d + 4) + hi) ^ (l31 & 7)) * 8));
      sa0 = __builtin_amdgcn_mfma_f32_32x32x16_bf16(kf0, qf[d], sa0, 0, 0, 0);
      sa1 = __builtin_amdgcn_mfma_f32_32x32x16_bf16(kf1, qf[d + 4], sa1, 0, 0, 0);
    }
    __builtin_amdgcn_s_setprio(0);
    f32x16 sa = sa0 + sa1;

    if (kt == qt) {  // causal mask, diagonal tile only (k > q -> exp2 -> 0)
      const int q = qh * 32 + l31;
#pragma unroll
      for (int r = 0; r < 16; r++)
        if (kh * 32 + (r & 3) + 8 * (r >> 2) + 4 * hi > q) sa[r] = -1e38f;
    }

    // P = exp2(S); l partial; truncate-pack; permlane32_swap -> PV B-fragments in-reg
    float ps[16];
#pragma unroll
    for (int r = 0; r < 16; r++) ps[r] = exp2f(sa[r]);
#pragma unroll
    for (int r = 0; r < 16; r++) lsum += ps[r];
    unsigned ub[4][2];
#pragma unroll
    for (int j = 0; j < 4; j++) {
      unsigned a0 = __builtin_bit_cast(unsigned, ps[4 * j + 0]);
      unsigned a1 = __builtin_bit_cast(unsigned, ps[4 * j + 1]);
      unsigned a2 = __builtin_bit_cast(unsigned, ps[4 * j + 2]);
      unsigned a3 = __builtin_bit_cast(unsigned, ps[4 * j + 3]);
      ub[j][0] = (a0 >> 16) | (a1 & 0xffff0000u);
      ub[j][1] = (a2 >> 16) | (a3 & 0xffff0000u);
    }
    bf16x8 pfrag[2];  // B-operand: P^T[k = ks*16 + hi*8 + i][q = l31], ks = kh*2+sub
#pragma unroll
    for (int sub = 0; sub < 2; sub++) {
      auto s0 = __builtin_amdgcn_permlane32_swap((int)ub[2 * sub][0], (int)ub[2 * sub + 1][0], false, false);
      auto s1 = __builtin_amdgcn_permlane32_swap((int)ub[2 * sub][1], (int)ub[2 * sub + 1][1], false, false);
      // new_dst = {A.lo, B.lo}, new_src = {A.hi, B.hi}
      uint4v uu;
      uu[0] = (unsigned)s0[0]; uu[1] = (unsigned)s1[0];
      uu[2] = (unsigned)s0[1]; uu[3] = (unsigned)s1[1];
      pfrag[sub] = __builtin_bit_cast(bf16x8, uu);
    }

    // O^T += V^T(own khalf) @ P^T   (waits vmcnt(4): V done, staging still in flight)
    __builtin_amdgcn_s_setprio(1);
#pragma unroll
    for (int dt = 0; dt < 4; dt++)
#pragma unroll
      for (int sub = 0; sub < 2; sub++)
        o_acc[dt] = __builtin_amdgcn_mfma_f32_32x32x16_bf16(vf[dt][sub], pfrag[sub], o_acc[dt], 0, 0, 0);
    __builtin_amdgcn_s_setprio(0);

    if (kt == qt) {  // segment end: combine k-halves, normalize, store, reset
      float lp = lsum + __shfl_xor(lsum, 32, 64);  // hi/lo subsets -> full khalf sum
      if (lane < 32) lbuf[w * 32 + l31] = lp;
      if (w >= 2) {  // khalf-1 waves export O^T tiles
        float* oex = Oex + (w - 2) * 4096;
#pragma unroll
        for (int dt = 0; dt < 4; dt++)
#pragma unroll
          for (int rq = 0; rq < 4; rq++) {
            f32x4 vv = {o_acc[dt][4 * rq + 0], o_acc[dt][4 * rq + 1],
                        o_acc[dt][4 * rq + 2], o_acc[dt][4 * rq + 3]};
            *reinterpret_cast<f32x4*>(oex + ((dt * 4 + rq) * 64 + lane) * 4) = vv;
          }
      }
      __syncthreads();
      if (w < 2) {  // khalf-0 waves combine + write ctx
        const float invl = 1.f / (lp + lbuf[(w ^ 2) * 32 + l31]);
        const float* oex = Oex + w * 4096;  // partner wave w+2's slot
        const size_t row = (size_t)(b * SEQ + qt * 64 + qh * 32 + l31);
#pragma unroll
        for (int dt = 0; dt < 4; dt++)
#pragma unroll
          for (int rq = 0; rq < 4; rq++) {
            f32x4 vv = *reinterpret_cast<const f32x4*>(oex + ((dt * 4 + rq) * 64 + lane) * 4);
            float e0 = (o_acc[dt][4 * rq + 0] + vv[0]) * invl;
            float e1 = (o_acc[dt][4 * rq + 1] + vv[1]) * invl;
            float e2 = (o_acc[dt][4 * rq + 2] + vv[2]) * invl;
            float e3 = (o_acc[dt][4 * rq + 3] + vv[3]) * invl;
            uint2 dd = make_uint2(pack2(e0, e1), pack2(e2, e3));
            *reinterpret_cast<uint2*>(ctx + row * 2048 + h * HD + dt * 32 + rq * 8 + hi * 4) = dd;
          }
      }
#pragma unroll
      for (int dt = 0; dt < 4; dt++)
#pragma unroll
        for (int e = 0; e < 16; e++) o_acc[dt][e] = 0.f;
      lsum = 0.f;
    }
  }
}

extern "C" void kernel_launch(void* const* d_in, const int* in_sizes, int n_in,
                              void* d_out, int out_size, void* d_ws, size_t ws_size,
                              hipStream_t stream) {
  const float* x  = (const float*)d_in[0];
  const float* Wq = (const float*)d_in[1];
  const float* Wk = (const float*)d_in[2];
  const float* Wv = (const float*)d_in[3];
  const float* Wo = (const float*)d_in[4];
  const float* bo = (const float*)d_in[5];
  float* out = (float*)d_out;

  // softmax scale folded into Q: (1/sqrt(128)) * log2(e)
  const float sc2 = 0.08838834764831845f * 1.4426950408889634f;

  // workspace layout (bf16 as short), total ~84 MB
  short* xb    = (short*)d_ws;                   // [4096][2048]
  short* WqkvT = xb    + (size_t)4096 * 2048;    // [3072][2048]  rows: WqT | WkT | WvT
  short* WoT   = WqkvT + (size_t)3072 * 2048;    // [2048][2048]
  short* qkv   = WoT   + (size_t)2048 * 2048;    // [4096][3072]
  short* vT    = qkv   + (size_t)4096 * 3072;    // [2*512][2048]
  short* ctx   = vT    + (size_t)1024 * 2048;    // [4096][2048]

  prep_kernel<<<dim3(18432), dim3(256), 0, stream>>>(x, Wq, Wk, Wv, Wo, xb, WqkvT, WoT);
  // qkv = xb @ WqkvT^T : M=4096, N=3072, K=2048; q cols pre-scaled by sc2
  gemm_bt_kernel<0><<<dim3(24, 32), dim3(256), 0, stream>>>(xb, WqkvT, qkv, nullptr,
                                                            4096, 3072, 2048, 2048, sc2);
  transpose_v_kernel<<<dim3(64, 16, 2), dim3(256), 0, stream>>>(qkv, vT);
  attn_kernel<<<dim3(512), dim3(256), 0, stream>>>(qkv, vT, ctx);
  // out = ctx @ WoT^T + bo : M=4096, N=2048, K=2048, fp32 epilogue
  gemm_bt_kernel<1><<<dim3(16, 32), dim3(256), 0, stream>>>(ctx, WoT, out, bo,
                                                            4096, 2048, 2048, 0, 1.0f);
}

// Round 3
// 281.265 us; speedup vs baseline: 1.1120x; 1.1120x over previous
//
#include <hip/hip_runtime.h>
#include <stdint.h>

typedef __attribute__((ext_vector_type(8))) __bf16 bf16x8;
typedef __attribute__((ext_vector_type(4))) float f32x4;
typedef __attribute__((ext_vector_type(16))) float f32x16;
typedef __attribute__((ext_vector_type(4))) short short4v;
typedef __attribute__((ext_vector_type(4))) unsigned uint4v;

// Problem constants
static constexpr int SEQ  = 2048;   // N
static constexpr int DQKV = 3072;   // q(2048) + k(512) + v(512)
static constexpr int HD   = 128;

// round-to-nearest-even fp32 -> bf16 bits
__device__ __forceinline__ short f2bf(float f) {
  unsigned u = __builtin_bit_cast(unsigned, f);
  u += 0x7fffu + ((u >> 16) & 1u);
  return (short)(u >> 16);
}

__device__ __forceinline__ unsigned pack2(float a, float b) {
  return (unsigned)(unsigned short)f2bf(a) | ((unsigned)(unsigned short)f2bf(b) << 16);
}

// async global->LDS, 16B per lane; LDS dest must be wave-uniform base + lane*16
__device__ __forceinline__ void gl_lds16(const void* g, void* l) {
  __builtin_amdgcn_global_load_lds(
      (const __attribute__((address_space(1))) void*)g,
      (__attribute__((address_space(3))) void*)l, 16, 0, 0);
}

// ---------------- fused prep: cast x + transpose-cast all weights ----------------
__global__ __launch_bounds__(256)
void prep_kernel(const float* __restrict__ x, const float* __restrict__ Wq,
                 const float* __restrict__ Wk, const float* __restrict__ Wv,
                 const float* __restrict__ Wo,
                 short* __restrict__ xb, short* __restrict__ WqkvT,
                 short* __restrict__ WoT) {
  int blk = blockIdx.x, tid = threadIdx.x;
  if (blk < 8192) {
    int i = blk * 256 + tid;
    float4 v = reinterpret_cast<const float4*>(x)[i];
    short4v o;
    o[0] = f2bf(v.x); o[1] = f2bf(v.y); o[2] = f2bf(v.z); o[3] = f2bf(v.w);
    *reinterpret_cast<short4v*>(xb + (size_t)i * 4) = o;
    return;
  }
  blk -= 8192;
  __shared__ float tile[32][33];
  const float* in; short* out; int C, bx, by;
  if (blk < 4096)      { in = Wq; out = WqkvT;                     C = 2048; bx = blk & 63; by = blk >> 6; }
  else if (blk < 5120) { int t = blk - 4096; in = Wk; out = WqkvT + (size_t)2048 * 2048; C = 512; bx = t & 15; by = t >> 4; }
  else if (blk < 6144) { int t = blk - 5120; in = Wv; out = WqkvT + (size_t)2560 * 2048; C = 512; bx = t & 15; by = t >> 4; }
  else                 { int t = blk - 6144; in = Wo; out = WoT;   C = 2048; bx = t & 63; by = t >> 6; }
  const int R = 2048;
  int c0 = bx * 32, r0 = by * 32, tx = tid & 31, ty = tid >> 5;
  for (int i = 0; i < 4; i++)
    tile[ty + i * 8][tx] = in[(size_t)(r0 + ty + i * 8) * C + c0 + tx];
  __syncthreads();
  for (int i = 0; i < 4; i++)
    out[(size_t)(c0 + ty + i * 8) * R + r0 + tx] = f2bf(tile[tx][ty + i * 8]);
}

// -------- transpose V section of qkv[4096][3072] -> vT[b*512 + gd][2048] bf16 --------
__global__ __launch_bounds__(256) void transpose_v_kernel(const short* __restrict__ qkv,
                                                          short* __restrict__ vT) {
  __shared__ short tile[32][33];
  int n0 = blockIdx.x * 32, c0 = blockIdx.y * 32, b = blockIdx.z;
  int tx = threadIdx.x & 31, ty = threadIdx.x >> 5;
  for (int i = 0; i < 4; i++)
    tile[ty + i * 8][tx] = qkv[(size_t)(b * SEQ + n0 + ty + i * 8) * DQKV + 2560 + c0 + tx];
  __syncthreads();
  for (int i = 0; i < 4; i++)
    vT[(size_t)(b * 512 + c0 + ty + i * 8) * SEQ + n0 + tx] = tile[tx][ty + i * 8];
}

// ---------------- bf16 GEMM, BK=64: C[M][N] = A[M][K] @ BT[N][K]^T ----------------
// 128x128 macro-tile, BK=64 in two 32-k slabs (32KB LDS) -> half the barrier
// crossings of BK=32 while staying at 3 blocks/CU (confirmed win R5->R6).
template <int F32OUT>
__global__ __launch_bounds__(256)
void gemm_bt_kernel(const short* __restrict__ A, const short* __restrict__ BT,
                    void* __restrict__ Cout, const float* __restrict__ bias,
                    int M, int N, int K, int qcols, float qscale) {
  __shared__ __align__(16) short As[8192];  // 2 kslabs x [128 rows][32 k]
  __shared__ __align__(16) short Bs[8192];
  const int tid = threadIdx.x, lane = tid & 63, w = tid >> 6;
  const int l15 = lane & 15, quad = lane >> 4, q8 = quad * 8;
  const int row0 = blockIdx.y * 128, col0 = blockIdx.x * 128;
  const int wm = (w >> 1) * 64, wn = (w & 1) * 64;
  f32x4 acc[4][4] = {};
  const short* ga0 = A  + (size_t)(row0 + w * 16 + (lane >> 2)) * K + (lane & 3) * 8;
  const short* gb0 = BT + (size_t)(col0 + w * 16 + (lane >> 2)) * K + (lane & 3) * 8;
  for (int kt = 0; kt < K; kt += 64) {
    for (int s = 0; s < 2; s++) {
      gl_lds16(ga0 + kt + s * 32,                  As + s * 4096 + w * 512);
      gl_lds16(ga0 + (size_t)64 * K + kt + s * 32, As + s * 4096 + 2048 + w * 512);
      gl_lds16(gb0 + kt + s * 32,                  Bs + s * 4096 + w * 512);
      gl_lds16(gb0 + (size_t)64 * K + kt + s * 32, Bs + s * 4096 + 2048 + w * 512);
    }
    __syncthreads();  // drains vmcnt -> staged tiles visible
    for (int s = 0; s < 2; s++) {
      bf16x8 af[4], bfr[4];
      for (int i = 0; i < 4; i++)
        af[i] = *reinterpret_cast<const bf16x8*>(As + s * 4096 + (wm + i * 16 + l15) * 32 + q8);
      for (int j = 0; j < 4; j++)
        bfr[j] = *reinterpret_cast<const bf16x8*>(Bs + s * 4096 + (wn + j * 16 + l15) * 32 + q8);
      for (int i = 0; i < 4; i++)
        for (int j = 0; j < 4; j++)
          acc[i][j] = __builtin_amdgcn_mfma_f32_16x16x32_bf16(af[i], bfr[j], acc[i][j], 0, 0, 0);
    }
    __syncthreads();  // protect LDS reuse next iteration
  }
  if (F32OUT) {
    float* C = (float*)Cout;
    for (int j = 0; j < 4; j++) {
      int col = col0 + wn + j * 16 + l15;
      float bv = bias[col];
      for (int i = 0; i < 4; i++)
        for (int r = 0; r < 4; r++)
          C[(size_t)(row0 + wm + i * 16 + quad * 4 + r) * N + col] = acc[i][j][r] + bv;
    }
  } else {
    short* C = (short*)Cout;
    for (int j = 0; j < 4; j++) {
      int col = col0 + wn + j * 16 + l15;
      float sc = (col < qcols) ? qscale : 1.0f;
      for (int i = 0; i < 4; i++)
        for (int r = 0; r < 4; r++)
          C[(size_t)(row0 + wm + i * 16 + quad * 4 + r) * N + col] = f2bf(acc[i][j][r] * sc);
    }
  }
}

// ---------------- flash attention, causal, GQA — v3 -------------------------------
// Round-2 post-mortem: wall time per k-iteration was ~6600 cy with ALL pipes idle.
// Root cause: per-iteration V fragments were gathered from global vT with 4KB-row
// strides -> every 16B/lane load touched 64 distinct cache lines (2048 L2 requests
// per block-iter vs 16 coalesced ones when LDS-staged). v3 restores coalesced
// global_load_lds V staging (double-buffered, XOR-swizzled [128d][64k] tile) while
// keeping the round-1/2 wins: 32x32x16 MFMA, P entirely in registers (trunc-pack +
// permlane32_swap), K LDS XOR-swizzle, O k-split across wave pairs. The O-exchange
// runs in 4 passes through an 8KB buffer so total LDS = 32+32+8+0.5 = 74KB ->
// still 2 blocks/CU. PV consumes LDS only, so the staging loads are the only
// outstanding vmcnt at the barrier (round-0 proven pipeline).
// LDS/block-iter: stage 32KB + K reads 32KB + V reads 32KB = 96KB, ~4-way max
// conflicts. Grid/pairing unchanged: 512 blocks, qt=31-p then qt=p, 33 iters each.
__global__ __launch_bounds__(256, 2)
void attn_kernel(const short* __restrict__ qkv, const short* __restrict__ vT,
                 short* __restrict__ ctx) {
  __shared__ __align__(16) short Ks[2 * 8192];  // dbuf x [64 k][16 chunks], swizzled
  __shared__ __align__(16) short Vs[2 * 8192];  // dbuf x [128 d][8 chunks], swizzled
  __shared__ __align__(16) float Oex[2048];     // 8KB: per-dt O^T exchange (4 passes)
  __shared__ float lbuf[4 * 32];                // per-wave khalf-partial l
  const int tid = threadIdx.x, lane = tid & 63, w = tid >> 6;
  const int l31 = lane & 31, hi = lane >> 5;
  const int qh = w & 1, kh = w >> 1;
  const int idx = blockIdx.x;
  const int p = idx >> 5, h = (idx >> 1) & 15, b = idx & 1, g = h >> 2;
  const int qtA = 31 - p, qtB = p;
  const int lenA = qtA + 1, total = lenA + qtB + 1;  // == 33 for every block

  // stage K[64k][128d] and V^T[128d][64k] tiles, both 16B-chunk XOR swizzled via
  // pre-swizzled global source + linear LDS dest (both-sides rule).
  auto stage = [&](int buf, int kt) {
    const short* gk = qkv + (size_t)(b * SEQ + kt * 64) * DQKV + 2048 + g * HD;
#pragma unroll
    for (int s = 0; s < 4; s++) {
      const int r = w * 16 + s * 4 + (lane >> 4);  // k row; 16 chunks/row
      gl_lds16(gk + (size_t)r * DQKV + ((lane & 15) ^ (r & 7)) * 8,
               Ks + buf * 8192 + (w * 16 + s * 4) * 128);
    }
    const short* gv = vT + (size_t)(b * 512 + g * HD) * SEQ + kt * 64;
#pragma unroll
    for (int s = 0; s < 4; s++) {
      const int r = w * 32 + s * 8 + (lane >> 3);  // d row; 8 chunks/row
      gl_lds16(gv + (size_t)r * SEQ + ((lane & 7) ^ (r & 7)) * 8,
               Vs + buf * 8192 + (w * 32 + s * 8) * 64);
    }
  };

  bf16x8 qf[8];          // Q^T fragments for current segment (32 q rows per wave)
  f32x16 o_acc[4] = {};  // O^T[d = dt*32 + crow][q = l31], own k-half only
  float lsum = 0.f;      // running sum of P over (own khalf, own hi-subset) per q=l31

  stage(0, 0);
  for (int t = 0; t < total; t++) {
    const int seg = (t >= lenA);
    const int kt = seg ? (t - lenA) : t;
    const int qt = seg ? qtB : qtA;
    const int cur = t & 1;
    __syncthreads();  // buf[cur] staged (drains vmcnt); all waves done with buf[cur^1]

    if (t + 1 < total) {
      const int nkt = (t + 1 >= lenA) ? (t + 1 - lenA) : (t + 1);
      stage(cur ^ 1, nkt);  // in flight until next __syncthreads
    }
    __builtin_amdgcn_sched_barrier(0);  // keep compute below the staging issue

    if (t == 0 || t == lenA) {  // segment start: load Q fragments
      const short* gq = qkv + (size_t)(b * SEQ + qt * 64 + qh * 32 + l31) * DQKV + h * HD + hi * 8;
#pragma unroll
      for (int d = 0; d < 8; d++) qf[d] = *reinterpret_cast<const bf16x8*>(gq + d * 16);
    }

    // S^T quadrant [32k x 32q] = K(khalf) @ Q(qhalf)^T, two independent chains
    const short* Kb = Ks + cur * 8192;
    f32x16 sa0 = {}, sa1 = {};
    __builtin_amdgcn_s_setprio(1);
#pragma unroll
    for (int d = 0; d < 4; d++) {
      bf16x8 kf0 = *reinterpret_cast<const bf16x8*>(
          Kb + (kh * 32 + l31) * 128 + (((2 * d + hi) ^ (l31 & 7)) * 8));
      bf16x8 kf1 = *reinterpret_cast<const bf16x8*>(
          Kb + (kh * 32 + l31) * 128 + (((2 * (d + 4) + hi) ^ (l31 & 7)) * 8));
      sa0 = __builtin_amdgcn_mfma_f32_32x32x16_bf16(kf0, qf[d], sa0, 0, 0, 0);
      sa1 = __builtin_amdgcn_mfma_f32_32x32x16_bf16(kf1, qf[d + 4], sa1, 0, 0, 0);
    }
    __builtin_amdgcn_s_setprio(0);
    f32x16 sa = sa0 + sa1;

    if (kt == qt) {  // causal mask, diagonal tile only (k > q -> exp2 -> 0)
      const int q = qh * 32 + l31;
#pragma unroll
      for (int r = 0; r < 16; r++)
        if (kh * 32 + (r & 3) + 8 * (r >> 2) + 4 * hi > q) sa[r] = -1e38f;
    }

    // P = exp2(S); l partial; truncate-pack; permlane32_swap -> PV B-fragments in-reg
    float ps[16];
#pragma unroll
    for (int r = 0; r < 16; r++) ps[r] = exp2f(sa[r]);
#pragma unroll
    for (int r = 0; r < 16; r++) lsum += ps[r];
    unsigned ub[4][2];
#pragma unroll
    for (int j = 0; j < 4; j++) {
      unsigned a0 = __builtin_bit_cast(unsigned, ps[4 * j + 0]);
      unsigned a1 = __builtin_bit_cast(unsigned, ps[4 * j + 1]);
      unsigned a2 = __builtin_bit_cast(unsigned, ps[4 * j + 2]);
      unsigned a3 = __builtin_bit_cast(unsigned, ps[4 * j + 3]);
      ub[j][0] = (a0 >> 16) | (a1 & 0xffff0000u);
      ub[j][1] = (a2 >> 16) | (a3 & 0xffff0000u);
    }
    bf16x8 pfrag[2];  // B-operand: P^T[k = ks*16 + hi*8 + i][q = l31], ks = kh*2+sub
#pragma unroll
    for (int sub = 0; sub < 2; sub++) {
      auto s0 = __builtin_amdgcn_permlane32_swap((int)ub[2 * sub][0], (int)ub[2 * sub + 1][0], false, false);
      auto s1 = __builtin_amdgcn_permlane32_swap((int)ub[2 * sub][1], (int)ub[2 * sub + 1][1], false, false);
      // new_dst = {A.lo, B.lo}, new_src = {A.hi, B.hi}
      uint4v uu;
      uu[0] = (unsigned)s0[0]; uu[1] = (unsigned)s1[0];
      uu[2] = (unsigned)s0[1]; uu[3] = (unsigned)s1[1];
      pfrag[sub] = __builtin_bit_cast(bf16x8, uu);
    }

    // O^T += V^T(own khalf) @ P^T ; V fragments from swizzled LDS tile
    const short* Vb = Vs + cur * 8192;
    __builtin_amdgcn_s_setprio(1);
#pragma unroll
    for (int dt = 0; dt < 4; dt++) {
#pragma unroll
      for (int sub = 0; sub < 2; sub++) {
        const int kc = kh * 4 + sub * 2 + hi;  // 8-k chunk index within 64k
        bf16x8 vf = *reinterpret_cast<const bf16x8*>(
            Vb + (dt * 32 + l31) * 64 + ((kc ^ (l31 & 7)) * 8));
        o_acc[dt] = __builtin_amdgcn_mfma_f32_32x32x16_bf16(vf, pfrag[sub], o_acc[dt], 0, 0, 0);
      }
    }
    __builtin_amdgcn_s_setprio(0);

    if (kt == qt) {  // segment end: combine k-halves (4 passes), normalize, store
      float lp = lsum + __shfl_xor(lsum, 32, 64);  // hi/lo subsets -> full khalf sum
      if (lane < 32) lbuf[w * 32 + l31] = lp;
      float invl = 0.f;
      const size_t row = (size_t)(b * SEQ + qt * 64 + qh * 32 + l31);
#pragma unroll
      for (int dt = 0; dt < 4; dt++) {
        if (w >= 2) {  // khalf-1 waves export this dt's O^T tile
          float* oex = Oex + (w - 2) * 1024;
#pragma unroll
          for (int rq = 0; rq < 4; rq++) {
            f32x4 vv = {o_acc[dt][4 * rq + 0], o_acc[dt][4 * rq + 1],
                        o_acc[dt][4 * rq + 2], o_acc[dt][4 * rq + 3]};
            *reinterpret_cast<f32x4*>(oex + (rq * 64 + lane) * 4) = vv;
          }
        }
        __syncthreads();
        if (w < 2) {  // khalf-0 waves combine + write ctx for this dt
          if (dt == 0) invl = 1.f / (lp + lbuf[(w ^ 2) * 32 + l31]);
          const float* oex = Oex + w * 1024;  // partner wave w+2's slot
#pragma unroll
          for (int rq = 0; rq < 4; rq++) {
            f32x4 vv = *reinterpret_cast<const f32x4*>(oex + (rq * 64 + lane) * 4);
            float e0 = (o_acc[dt][4 * rq + 0] + vv[0]) * invl;
            float e1 = (o_acc[dt][4 * rq + 1] + vv[1]) * invl;
            float e2 = (o_acc[dt][4 * rq + 2] + vv[2]) * invl;
            float e3 = (o_acc[dt][4 * rq + 3] + vv[3]) * invl;
            uint2 dd = make_uint2(pack2(e0, e1), pack2(e2, e3));
            *reinterpret_cast<uint2*>(ctx + row * 2048 + h * HD + dt * 32 + rq * 8 + hi * 4) = dd;
          }
        }
        __syncthreads();  // Oex free for next pass
      }
#pragma unroll
      for (int dt = 0; dt < 4; dt++)
#pragma unroll
        for (int e = 0; e < 16; e++) o_acc[dt][e] = 0.f;
      lsum = 0.f;
    }
  }
}

extern "C" void kernel_launch(void* const* d_in, const int* in_sizes, int n_in,
                              void* d_out, int out_size, void* d_ws, size_t ws_size,
                              hipStream_t stream) {
  const float* x  = (const float*)d_in[0];
  const float* Wq = (const float*)d_in[1];
  const float* Wk = (const float*)d_in[2];
  const float* Wv = (const float*)d_in[3];
  const float* Wo = (const float*)d_in[4];
  const float* bo = (const float*)d_in[5];
  float* out = (float*)d_out;

  // softmax scale folded into Q: (1/sqrt(128)) * log2(e)
  const float sc2 = 0.08838834764831845f * 1.4426950408889634f;

  // workspace layout (bf16 as short), total ~84 MB
  short* xb    = (short*)d_ws;                   // [4096][2048]
  short* WqkvT = xb    + (size_t)4096 * 2048;    // [3072][2048]  rows: WqT | WkT | WvT
  short* WoT   = WqkvT + (size_t)3072 * 2048;    // [2048][2048]
  short* qkv   = WoT   + (size_t)2048 * 2048;    // [4096][3072]
  short* vT    = qkv   + (size_t)4096 * 3072;    // [2*512][2048]
  short* ctx   = vT    + (size_t)1024 * 2048;    // [4096][2048]

  prep_kernel<<<dim3(18432), dim3(256), 0, stream>>>(x, Wq, Wk, Wv, Wo, xb, WqkvT, WoT);
  // qkv = xb @ WqkvT^T : M=4096, N=3072, K=2048; q cols pre-scaled by sc2
  gemm_bt_kernel<0><<<dim3(24, 32), dim3(256), 0, stream>>>(xb, WqkvT, qkv, nullptr,
                                                            4096, 3072, 2048, 2048, sc2);
  transpose_v_kernel<<<dim3(64, 16, 2), dim3(256), 0, stream>>>(qkv, vT);
  attn_kernel<<<dim3(512), dim3(256), 0, stream>>>(qkv, vT, ctx);
  // out = ctx @ WoT^T + bo : M=4096, N=2048, K=2048, fp32 epilogue
  gemm_bt_kernel<1><<<dim3(16, 32), dim3(256), 0, stream>>>(ctx, WoT, out, bo,
                                                            4096, 2048, 2048, 0, 1.0f);
}